// Round 1
// baseline (841.828 us; speedup 1.0000x reference)
//
#include <hip/hip_runtime.h>
#include <math.h>

// ---------------------------------------------------------------------------
// Quantized bottleneck block, fp32 baseline (Round 0).
//   conv1: 1x1 512->128  + bn1 + relu + bfp_quant
//   conv2: 3x3 128->128  + bn2 + relu + bfp_quant
//   conv3: 1x1 128->512  + bn3 + residual + relu + bfp_quant
// Weight quant: per (o, in-block-of-32, kh, kw) scale alpha = max|w|/127.
// Activation quant: per (pixel, channel-block-of-32) shared exponent.
// ---------------------------------------------------------------------------

#define N_IMG 64
#define HH 28
#define WW 28
#define HW 784            // 28*28
#define CIN 512
#define CMID 128
#define COUT 512
#define PTOT (N_IMG * HW) // 50176
#define PT 64             // pixel tile
#define OT 64             // output-channel tile
#define KB 32             // k-block (matches quant block size)

// ---------------------------------------------------------------------------
// Weight quantization: w [O][I][KHW] -> wt [KHW*I][O] (transposed, quantized)
// alpha per (o, i-block-of-32, khw). Matches numpy bitwise (IEEE div/rint/mul).
// ---------------------------------------------------------------------------
__global__ void wquant_kernel(const float* __restrict__ w, float* __restrict__ wt,
                              int O, int I, int KHW) {
  int task = blockIdx.x * blockDim.x + threadIdx.x;
  int nblk = I / 32;
  int total = O * nblk * KHW;
  if (task >= total) return;
  int khw = task % KHW;
  int tmp = task / KHW;
  int cb = tmp % nblk;
  int o = tmp / nblk;

  float vals[32];
  float mx = 0.0f;
#pragma unroll
  for (int j = 0; j < 32; ++j) {
    float vv = w[(o * I + cb * 32 + j) * KHW + khw];
    vals[j] = vv;
    mx = fmaxf(mx, fabsf(vv));
  }
  float alpha = fmaxf(__fdiv_rn(mx, 127.0f), 1e-24f);
#pragma unroll
  for (int j = 0; j < 32; ++j) {
    float q = __fmul_rn(rintf(__fdiv_rn(vals[j], alpha)), alpha);
    wt[(khw * I + cb * 32 + j) * O + o] = q;
  }
}

// ---------------------------------------------------------------------------
// Shared epilogue helper (bn + optional residual + relu + bfp_quant) is inlined
// in each conv kernel (needs the block's LDS tile).
// ---------------------------------------------------------------------------

// 1x1 conv as GEMM: out[p, o] = sum_c in[p, c] * wt[c, o]
__global__ __launch_bounds__(256) void conv1x1_bfp(
    const float* __restrict__ in,   // [N][Cin][784]
    const float* __restrict__ wt,   // [Cin][Cout]
    const float* __restrict__ gg, const float* __restrict__ bb,
    const float* __restrict__ mm, const float* __restrict__ vv,
    const float* __restrict__ resid, // x (for conv3) or nullptr
    float* __restrict__ out,        // [N][Cout][784]
    int Cin, int Cout, int doResid) {
  __shared__ float As[KB][PT];
  __shared__ float Bs[KB][OT];
  __shared__ float Cs[PT][OT + 1];
  __shared__ float Dd[PT][2];
  __shared__ float Di[PT][2];
  __shared__ int ibase[PT];
  __shared__ int obase[PT];

  const int t = threadIdx.x;
  const int p0 = blockIdx.x * PT;
  const int og = blockIdx.y * OT;

  if (t < PT) {
    int p = p0 + t;
    int n = p / HW;
    int hw = p % HW;
    ibase[t] = n * Cin * HW + hw;
    obase[t] = n * Cout * HW + hw;
  }

  float acc[4][4] = {};
  const int pi = t & 15;  // pixel group (4 px each)
  const int oi = t >> 4;  // out-channel group (4 o each)
  const int i64 = t & 63;
  const int q4 = t >> 6;  // 0..3
  const int kIters = Cin / KB;

  for (int kb = 0; kb < kIters; ++kb) {
    __syncthreads();
#pragma unroll
    for (int j = 0; j < 8; ++j) {
      int cl = q4 + j * 4;
      As[cl][i64] = in[ibase[i64] + (kb * KB + cl) * HW];
    }
#pragma unroll
    for (int j = 0; j < 8; ++j) {
      int kl = q4 + j * 4;
      Bs[kl][i64] = wt[(kb * KB + kl) * Cout + og + i64];
    }
    __syncthreads();
#pragma unroll
    for (int k = 0; k < KB; ++k) {
      const float4 a = *(const float4*)(&As[k][pi * 4]);
      const float4 w4 = *(const float4*)(&Bs[k][oi * 4]);
      const float av[4] = {a.x, a.y, a.z, a.w};
      const float wv[4] = {w4.x, w4.y, w4.z, w4.w};
#pragma unroll
      for (int pp = 0; pp < 4; ++pp)
#pragma unroll
        for (int oo = 0; oo < 4; ++oo) acc[pp][oo] += av[pp] * wv[oo];
    }
  }

  // epilogue: bn (+residual) + relu into Cs
  float inv[4], ct[4];
#pragma unroll
  for (int oo = 0; oo < 4; ++oo) {
    int o = og + oi * 4 + oo;
    float iv = gg[o] / sqrtf(__fadd_rn(vv[o], 1e-5f));
    inv[oo] = iv;
    ct[oo] = __fsub_rn(bb[o], __fmul_rn(mm[o], iv));
  }
#pragma unroll
  for (int pp = 0; pp < 4; ++pp) {
    int px = pi * 4 + pp;
#pragma unroll
    for (int oo = 0; oo < 4; ++oo) {
      float val = __fadd_rn(__fmul_rn(acc[pp][oo], inv[oo]), ct[oo]);
      if (doResid) {
        int o = og + oi * 4 + oo;
        val = __fadd_rn(val, resid[obase[px] + o * HW]);
      }
      val = fmaxf(val, 0.0f);
      Cs[px][oi * 4 + oo] = val;
    }
  }
  __syncthreads();
  // per (pixel, 32-channel group) shared exponent
  if (t < PT * 2) {
    int px = t & 63;
    int grp = t >> 6;
    float mx = 0.0f;
#pragma unroll
    for (int j = 0; j < 32; ++j) mx = fmaxf(mx, fabsf(Cs[px][grp * 32 + j]));
    mx = fmaxf(mx, 1e-24f);
    float e = floorf(log2f(mx));
    Dd[px][grp] = exp2f(e - 6.0f);
    Di[px][grp] = exp2f(6.0f - e);
  }
  __syncthreads();
#pragma unroll
  for (int rep = 0; rep < 16; ++rep) {
    int ol = rep * 4 + q4;
    int px = i64;
    float val = Cs[px][ol];
    int grp = ol >> 5;
    float q = rintf(__fmul_rn(val, Di[px][grp]));
    q = fminf(fmaxf(q, -128.0f), 127.0f);
    out[obase[px] + (og + ol) * HW] = __fmul_rn(q, Dd[px][grp]);
  }
}

// 3x3 conv (pad 1) as GEMM with on-the-fly im2col. K = (ky,kx,c) = 1152.
__global__ __launch_bounds__(256) void conv3x3_bfp(
    const float* __restrict__ in,   // [N][128][784]
    const float* __restrict__ wt,   // [1152][128], k = (ky*3+kx)*128 + c
    const float* __restrict__ gg, const float* __restrict__ bb,
    const float* __restrict__ mm, const float* __restrict__ vv,
    float* __restrict__ out) {      // [N][128][784]
  __shared__ float As[KB][PT];
  __shared__ float Bs[KB][OT];
  __shared__ float Cs[PT][OT + 1];
  __shared__ float Dd[PT][2];
  __shared__ float Di[PT][2];
  __shared__ int nbase[PT];
  __shared__ int obase[PT];
  __shared__ int pxh[PT];
  __shared__ int pxw[PT];

  const int t = threadIdx.x;
  const int p0 = blockIdx.x * PT;
  const int og = blockIdx.y * OT;

  if (t < PT) {
    int p = p0 + t;
    int n = p / HW;
    int hw = p % HW;
    nbase[t] = n * CMID * HW;
    obase[t] = n * CMID * HW + hw;
    pxh[t] = hw / WW;
    pxw[t] = hw % WW;
  }

  float acc[4][4] = {};
  const int pi = t & 15;
  const int oi = t >> 4;
  const int i64 = t & 63;
  const int q4 = t >> 6;

  for (int kb = 0; kb < 36; ++kb) {
    int khw = kb >> 2;
    int cb = kb & 3;
    int ky = khw / 3;
    int kx = khw % 3;
    __syncthreads();
#pragma unroll
    for (int j = 0; j < 8; ++j) {
      int cl = q4 + j * 4;
      int h2 = pxh[i64] + ky - 1;
      int w2 = pxw[i64] + kx - 1;
      bool ok = ((unsigned)h2 < 28u) && ((unsigned)w2 < 28u);
      As[cl][i64] = ok ? in[nbase[i64] + (cb * 32 + cl) * HW + h2 * WW + w2] : 0.0f;
    }
#pragma unroll
    for (int j = 0; j < 8; ++j) {
      int kl = q4 + j * 4;
      Bs[kl][i64] = wt[(khw * CMID + cb * 32 + kl) * CMID + og + i64];
    }
    __syncthreads();
#pragma unroll
    for (int k = 0; k < KB; ++k) {
      const float4 a = *(const float4*)(&As[k][pi * 4]);
      const float4 w4 = *(const float4*)(&Bs[k][oi * 4]);
      const float av[4] = {a.x, a.y, a.z, a.w};
      const float wv[4] = {w4.x, w4.y, w4.z, w4.w};
#pragma unroll
      for (int pp = 0; pp < 4; ++pp)
#pragma unroll
        for (int oo = 0; oo < 4; ++oo) acc[pp][oo] += av[pp] * wv[oo];
    }
  }

  float inv[4], ct[4];
#pragma unroll
  for (int oo = 0; oo < 4; ++oo) {
    int o = og + oi * 4 + oo;
    float iv = gg[o] / sqrtf(__fadd_rn(vv[o], 1e-5f));
    inv[oo] = iv;
    ct[oo] = __fsub_rn(bb[o], __fmul_rn(mm[o], iv));
  }
#pragma unroll
  for (int pp = 0; pp < 4; ++pp) {
    int px = pi * 4 + pp;
#pragma unroll
    for (int oo = 0; oo < 4; ++oo) {
      float val = __fadd_rn(__fmul_rn(acc[pp][oo], inv[oo]), ct[oo]);
      val = fmaxf(val, 0.0f);
      Cs[px][oi * 4 + oo] = val;
    }
  }
  __syncthreads();
  if (t < PT * 2) {
    int px = t & 63;
    int grp = t >> 6;
    float mx = 0.0f;
#pragma unroll
    for (int j = 0; j < 32; ++j) mx = fmaxf(mx, fabsf(Cs[px][grp * 32 + j]));
    mx = fmaxf(mx, 1e-24f);
    float e = floorf(log2f(mx));
    Dd[px][grp] = exp2f(e - 6.0f);
    Di[px][grp] = exp2f(6.0f - e);
  }
  __syncthreads();
#pragma unroll
  for (int rep = 0; rep < 16; ++rep) {
    int ol = rep * 4 + q4;
    int px = i64;
    float val = Cs[px][ol];
    int grp = ol >> 5;
    float q = rintf(__fmul_rn(val, Di[px][grp]));
    q = fminf(fmaxf(q, -128.0f), 127.0f);
    out[obase[px] + (og + ol) * HW] = __fmul_rn(q, Dd[px][grp]);
  }
}

extern "C" void kernel_launch(void* const* d_in, const int* in_sizes, int n_in,
                              void* d_out, int out_size, void* d_ws, size_t ws_size,
                              hipStream_t stream) {
  (void)in_sizes; (void)n_in; (void)out_size; (void)ws_size;
  const float* x = (const float*)d_in[0];
  const float* w1 = (const float*)d_in[1];
  const float* w2 = (const float*)d_in[2];
  const float* w3 = (const float*)d_in[3];
  const float* bn1g = (const float*)d_in[4];
  const float* bn1b = (const float*)d_in[5];
  const float* bn1m = (const float*)d_in[6];
  const float* bn1v = (const float*)d_in[7];
  const float* bn2g = (const float*)d_in[8];
  const float* bn2b = (const float*)d_in[9];
  const float* bn2m = (const float*)d_in[10];
  const float* bn2v = (const float*)d_in[11];
  const float* bn3g = (const float*)d_in[12];
  const float* bn3b = (const float*)d_in[13];
  const float* bn3m = (const float*)d_in[14];
  const float* bn3v = (const float*)d_in[15];
  float* out = (float*)d_out;

  float* ws = (float*)d_ws;
  float* wq1t = ws;                    // [512][128]   = 65536
  float* wq2t = wq1t + 512 * 128;      // [1152][128]  = 147456
  float* wq3t = wq2t + 1152 * 128;     // [128][512]   = 65536
  float* a1 = wq3t + 128 * 512;        // [64][128][784] = 6422528
  float* a2 = a1 + (size_t)N_IMG * CMID * HW;

  // weight quantization (transposed outputs)
  wquant_kernel<<<8, 256, 0, stream>>>(w1, wq1t, 128, 512, 1);
  wquant_kernel<<<18, 256, 0, stream>>>(w2, wq2t, 128, 128, 9);
  wquant_kernel<<<8, 256, 0, stream>>>(w3, wq3t, 512, 128, 1);

  dim3 blk(256);
  dim3 g1(PTOT / PT, CMID / OT);  // (784, 2)
  conv1x1_bfp<<<g1, blk, 0, stream>>>(x, wq1t, bn1g, bn1b, bn1m, bn1v, nullptr,
                                      a1, CIN, CMID, 0);
  dim3 g2(PTOT / PT, CMID / OT);  // (784, 2)
  conv3x3_bfp<<<g2, blk, 0, stream>>>(a1, wq2t, bn2g, bn2b, bn2m, bn2v, a2);
  dim3 g3(PTOT / PT, COUT / OT);  // (784, 8)
  conv1x1_bfp<<<g3, blk, 0, stream>>>(a2, wq3t, bn3g, bn3b, bn3m, bn3v, x, out,
                                      CMID, COUT, 1);
}

// Round 4
// 441.512 us; speedup vs baseline: 1.9067x; 1.9067x over previous
//
#include <hip/hip_runtime.h>
#include <math.h>

// ---------------------------------------------------------------------------
// Round 4 (= Round 3 resubmit, infra timeout): MFMA bf16.
//   conv1: reads x NCHW fp32, LDS-stages exact hi/lo bf16 pairs (K=1024 GEMM)
//          -> bn1+relu+bfp -> a1 NHWC bf16 (exact)
//   conv2: GEMM K=1152 (9 taps x 128c, on-the-fly im2col via per-tap ptrs)
//   conv3: GEMM K=128 -> bn3 + residual + relu + bfp -> out NCHW fp32
// Weights quantized per reference then rounded to bf16 (rel err 2^-9, well
// under activation quant steps). Activations after bfp_quant are EXACT bf16.
// ws usage ~26.4 MB.
// ---------------------------------------------------------------------------

#define HW 784
#define WW 28
#define PTOT 50176   // 64*784

typedef short s8v __attribute__((ext_vector_type(8)));
typedef float f4v __attribute__((ext_vector_type(4)));

__device__ __forceinline__ f4v mfma16(s8v a, s8v b, f4v c) {
  return __builtin_amdgcn_mfma_f32_16x16x32_bf16(a, b, c, 0, 0, 0);
}

__device__ __forceinline__ unsigned short f2bf(float f) {
  unsigned u = __float_as_uint(f);
  u += 0x7fffu + ((u >> 16) & 1u);
  return (unsigned short)(u >> 16);
}
__device__ __forceinline__ float bf2f(unsigned short h) {
  return __uint_as_float(((unsigned)h) << 16);
}

// ---------------------------------------------------------------------------
// Weight quantization kernels -> bf16, [o][k] layouts
// ---------------------------------------------------------------------------
__global__ void wq1_kernel(const float* __restrict__ w, unsigned short* __restrict__ wd) {
  int task = blockIdx.x * blockDim.x + threadIdx.x;  // o(128) x cb(16)
  if (task >= 128 * 16) return;
  int cb = task & 15, o = task >> 4;
  const float* src = w + o * 512 + cb * 32;
  float vals[32], mx = 0.f;
#pragma unroll
  for (int j = 0; j < 32; ++j) { vals[j] = src[j]; mx = fmaxf(mx, fabsf(vals[j])); }
  float alpha = fmaxf(__fdiv_rn(mx, 127.0f), 1e-24f);
#pragma unroll
  for (int j = 0; j < 32; ++j) {
    unsigned short q = f2bf(__fmul_rn(rintf(__fdiv_rn(vals[j], alpha)), alpha));
    wd[o * 1024 + (cb * 32 + j) * 2] = q;      // hi slot
    wd[o * 1024 + (cb * 32 + j) * 2 + 1] = q;  // lo slot (same weight)
  }
}

__global__ void wq2_kernel(const float* __restrict__ w, unsigned short* __restrict__ wd) {
  int task = blockIdx.x * blockDim.x + threadIdx.x;  // o(128) x cb(4) x khw(9)
  if (task >= 128 * 36) return;
  int o = task / 36, rem = task % 36;
  int khw = rem % 9, cb = rem / 9;
  float vals[32], mx = 0.f;
#pragma unroll
  for (int j = 0; j < 32; ++j) {
    vals[j] = w[(o * 128 + cb * 32 + j) * 9 + khw];
    mx = fmaxf(mx, fabsf(vals[j]));
  }
  float alpha = fmaxf(__fdiv_rn(mx, 127.0f), 1e-24f);
#pragma unroll
  for (int j = 0; j < 32; ++j)
    wd[o * 1152 + khw * 128 + cb * 32 + j] =
        f2bf(__fmul_rn(rintf(__fdiv_rn(vals[j], alpha)), alpha));
}

__global__ void wq3_kernel(const float* __restrict__ w, unsigned short* __restrict__ wd) {
  int task = blockIdx.x * blockDim.x + threadIdx.x;  // o(512) x cb(4)
  if (task >= 512 * 4) return;
  int cb = task & 3, o = task >> 2;
  const float* src = w + o * 128 + cb * 32;
  float vals[32], mx = 0.f;
#pragma unroll
  for (int j = 0; j < 32; ++j) { vals[j] = src[j]; mx = fmaxf(mx, fabsf(vals[j])); }
  float alpha = fmaxf(__fdiv_rn(mx, 127.0f), 1e-24f);
#pragma unroll
  for (int j = 0; j < 32; ++j)
    wd[o * 128 + cb * 32 + j] = f2bf(__fmul_rn(rintf(__fdiv_rn(vals[j], alpha)), alpha));
}

// ---------------------------------------------------------------------------
// conv1 fused: x NCHW fp32 -> (hi/lo split in LDS) -> GEMM K=1024 ->
// bn1+relu+bfp -> a1 NHWC bf16. Block: 256 thr / 4 waves, 64 px x 128 o.
// ---------------------------------------------------------------------------
__global__ __launch_bounds__(256) void conv1_fused(
    const float* __restrict__ x, const unsigned short* __restrict__ Wq,
    const float* __restrict__ gg, const float* __restrict__ bb,
    const float* __restrict__ mm, const float* __restrict__ vv,
    unsigned short* __restrict__ out16) {
  __shared__ unsigned short As[64][72];  // 64 px x 64 kslots (+8 pad)

  const int t = threadIdx.x;
  const int w = t >> 6, l = t & 63;
  const int col = l & 15, row4 = l >> 4;
  const int P0 = blockIdx.x * 64;
  const int OG = w * 32;
  const int k0 = row4 * 8;

  const int p = P0 + l;
  const int n = p / HW;
  const int hw = p - n * HW;
  const float* xbase = x + (size_t)n * 512 * HW + hw;

  f4v acc[4][2];
#pragma unroll
  for (int pg = 0; pg < 4; ++pg)
#pragma unroll
    for (int og = 0; og < 2; ++og) acc[pg][og] = (f4v){0.f, 0.f, 0.f, 0.f};

  float xr[8];
#pragma unroll
  for (int j = 0; j < 8; ++j) xr[j] = xbase[(w * 8 + j) * HW];

  for (int s = 0; s < 16; ++s) {
    if (s) __syncthreads();  // previous stage's LDS reads complete
    // convert to hi/lo pairs and write 16 shorts (2 x b128)
    s8v sv0, sv1;
#pragma unroll
    for (int j = 0; j < 4; ++j) {
      unsigned short hi = f2bf(xr[j]);
      float lo = __fsub_rn(xr[j], bf2f(hi));
      sv0[2 * j] = (short)hi;
      sv0[2 * j + 1] = (short)f2bf(lo);
    }
#pragma unroll
    for (int j = 0; j < 4; ++j) {
      unsigned short hi = f2bf(xr[4 + j]);
      float lo = __fsub_rn(xr[4 + j], bf2f(hi));
      sv1[2 * j] = (short)hi;
      sv1[2 * j + 1] = (short)f2bf(lo);
    }
    *(s8v*)&As[l][w * 16] = sv0;
    *(s8v*)&As[l][w * 16 + 8] = sv1;
    __syncthreads();
    // prefetch next stage while this stage computes
    if (s < 15) {
#pragma unroll
      for (int j = 0; j < 8; ++j) xr[j] = xbase[((s + 1) * 32 + w * 8 + j) * HW];
    }
#pragma unroll
    for (int kk = 0; kk < 2; ++kk) {
      s8v b0 = *(const s8v*)(Wq + (size_t)(OG + col) * 1024 + s * 64 + kk * 32 + k0);
      s8v b1 = *(const s8v*)(Wq + (size_t)(OG + 16 + col) * 1024 + s * 64 + kk * 32 + k0);
#pragma unroll
      for (int pg = 0; pg < 4; ++pg) {
        s8v af = *(const s8v*)&As[pg * 16 + col][kk * 32 + k0];
        acc[pg][0] = mfma16(af, b0, acc[pg][0]);
        acc[pg][1] = mfma16(af, b1, acc[pg][1]);
      }
    }
  }

  // epilogue: bn + relu + bfp quant -> a1 NHWC bf16
  float inv_[2], ct_[2];
#pragma unroll
  for (int og = 0; og < 2; ++og) {
    int o = OG + og * 16 + col;
    float iv = __fdiv_rn(gg[o], sqrtf(__fadd_rn(vv[o], 1e-5f)));
    inv_[og] = iv;
    ct_[og] = __fsub_rn(bb[o], __fmul_rn(mm[o], iv));
  }
#pragma unroll
  for (int pg = 0; pg < 4; ++pg) {
#pragma unroll
    for (int r = 0; r < 4; ++r) {
      const int px = P0 + pg * 16 + row4 * 4 + r;
      float v0 = __fadd_rn(__fmul_rn(acc[pg][0][r], inv_[0]), ct_[0]);
      float v1 = __fadd_rn(__fmul_rn(acc[pg][1][r], inv_[1]), ct_[1]);
      v0 = fmaxf(v0, 0.f);
      v1 = fmaxf(v1, 0.f);
      float mx = fmaxf(v0, v1);
#pragma unroll
      for (int sfl = 1; sfl < 16; sfl <<= 1) mx = fmaxf(mx, __shfl_xor(mx, sfl));
      mx = fmaxf(mx, 1e-24f);
      int e = (int)(__float_as_uint(mx) >> 23) - 127;
      float dlt = __uint_as_float((unsigned)(e - 6 + 127) << 23);
      float idlt = __uint_as_float((unsigned)(6 - e + 127) << 23);
      float q0 = fminf(fmaxf(rintf(__fmul_rn(v0, idlt)), -128.f), 127.f);
      float q1 = fminf(fmaxf(rintf(__fmul_rn(v1, idlt)), -128.f), 127.f);
      out16[(size_t)px * 128 + OG + col] = f2bf(__fmul_rn(q0, dlt));
      out16[(size_t)px * 128 + OG + 16 + col] = f2bf(__fmul_rn(q1, dlt));
    }
  }
}

// ---------------------------------------------------------------------------
// GEMM template. MODE 1: 3x3 taps (conv2), bf16 NHWC out.
// MODE 2: flat A (conv3) + residual + fp32 NCHW out.
// Block: 256 thr = 4 waves; tile 64 px x 128 o; wave = 64 px x 32 o.
// ---------------------------------------------------------------------------
template <int KDIM, int MODE>
__global__ __launch_bounds__(256) void gemm_bfp(
    const unsigned short* __restrict__ A, const unsigned short* __restrict__ Wq,
    const float* __restrict__ gg, const float* __restrict__ bb,
    const float* __restrict__ mm, const float* __restrict__ vv,
    const float* __restrict__ resid, void* __restrict__ outp,
    const unsigned short* __restrict__ zp) {
  const int t = threadIdx.x;
  const int w = t >> 6, l = t & 63;
  const int col = l & 15, row4 = l >> 4;
  const int P0 = blockIdx.x * 64;
  const int OG = blockIdx.y * 128 + w * 32;
  const int k0 = row4 * 8;

  int pxl[4];
#pragma unroll
  for (int pg = 0; pg < 4; ++pg) pxl[pg] = P0 + pg * 16 + col;

  const unsigned short* bbase[2];
#pragma unroll
  for (int og = 0; og < 2; ++og)
    bbase[og] = Wq + (size_t)(OG + og * 16 + col) * KDIM + k0;

  f4v acc[4][2];
#pragma unroll
  for (int pg = 0; pg < 4; ++pg)
#pragma unroll
    for (int og = 0; og < 2; ++og) acc[pg][og] = (f4v){0.f, 0.f, 0.f, 0.f};

  if (MODE == 1) {
    int hh[4], wl[4], nb[4];
#pragma unroll
    for (int pg = 0; pg < 4; ++pg) {
      int p = pxl[pg];
      int n = p / HW, hw = p - n * HW;
      hh[pg] = hw / WW;
      wl[pg] = hw - hh[pg] * WW;
      nb[pg] = n * HW;
    }
#pragma unroll
    for (int ty = 0; ty < 3; ++ty)
#pragma unroll
      for (int tx = 0; tx < 3; ++tx) {
        const int tap = ty * 3 + tx;
        const unsigned short* ab[4];
#pragma unroll
        for (int pg = 0; pg < 4; ++pg) {
          int h2 = hh[pg] + ty - 1, w2 = wl[pg] + tx - 1;
          bool ok = ((unsigned)h2 < 28u) & ((unsigned)w2 < 28u);
          ab[pg] = ok ? (A + (size_t)(nb[pg] + h2 * WW + w2) * 128 + k0) : (zp + k0);
        }
#pragma unroll
        for (int cb = 0; cb < 4; ++cb) {
          s8v bf0 = *(const s8v*)(bbase[0] + tap * 128 + cb * 32);
          s8v bf1 = *(const s8v*)(bbase[1] + tap * 128 + cb * 32);
#pragma unroll
          for (int pg = 0; pg < 4; ++pg) {
            s8v af = *(const s8v*)(ab[pg] + cb * 32);
            acc[pg][0] = mfma16(af, bf0, acc[pg][0]);
            acc[pg][1] = mfma16(af, bf1, acc[pg][1]);
          }
        }
      }
  } else {
    const unsigned short* ab[4];
#pragma unroll
    for (int pg = 0; pg < 4; ++pg) ab[pg] = A + (size_t)pxl[pg] * KDIM + k0;
#pragma unroll
    for (int kb = 0; kb < KDIM / 32; ++kb) {
      s8v bf0 = *(const s8v*)(bbase[0] + kb * 32);
      s8v bf1 = *(const s8v*)(bbase[1] + kb * 32);
#pragma unroll
      for (int pg = 0; pg < 4; ++pg) {
        s8v af = *(const s8v*)(ab[pg] + kb * 32);
        acc[pg][0] = mfma16(af, bf0, acc[pg][0]);
        acc[pg][1] = mfma16(af, bf1, acc[pg][1]);
      }
    }
  }

  // epilogue: bn (+resid) + relu + bfp quant
  float inv_[2], ct_[2];
#pragma unroll
  for (int og = 0; og < 2; ++og) {
    int o = OG + og * 16 + col;
    float iv = __fdiv_rn(gg[o], sqrtf(__fadd_rn(vv[o], 1e-5f)));
    inv_[og] = iv;
    ct_[og] = __fsub_rn(bb[o], __fmul_rn(mm[o], iv));
  }

#pragma unroll
  for (int pg = 0; pg < 4; ++pg) {
#pragma unroll
    for (int r = 0; r < 4; ++r) {
      const int px = P0 + pg * 16 + row4 * 4 + r;
      float v0 = __fadd_rn(__fmul_rn(acc[pg][0][r], inv_[0]), ct_[0]);
      float v1 = __fadd_rn(__fmul_rn(acc[pg][1][r], inv_[1]), ct_[1]);
      int n = 0, hw = 0;
      if (MODE == 2) {
        n = px / HW;
        hw = px - n * HW;
        v0 = __fadd_rn(v0, resid[((size_t)n * 512 + OG + col) * HW + hw]);
        v1 = __fadd_rn(v1, resid[((size_t)n * 512 + OG + 16 + col) * HW + hw]);
      }
      v0 = fmaxf(v0, 0.f);
      v1 = fmaxf(v1, 0.f);
      float mx = fmaxf(v0, v1);
#pragma unroll
      for (int sfl = 1; sfl < 16; sfl <<= 1) mx = fmaxf(mx, __shfl_xor(mx, sfl));
      mx = fmaxf(mx, 1e-24f);
      int e = (int)(__float_as_uint(mx) >> 23) - 127;
      float dlt = __uint_as_float((unsigned)(e - 6 + 127) << 23);
      float idlt = __uint_as_float((unsigned)(6 - e + 127) << 23);
      float q0 = fminf(fmaxf(rintf(__fmul_rn(v0, idlt)), -128.f), 127.f);
      float q1 = fminf(fmaxf(rintf(__fmul_rn(v1, idlt)), -128.f), 127.f);
      float o0 = __fmul_rn(q0, dlt), o1 = __fmul_rn(q1, dlt);
      if (MODE == 2) {
        float* outf = (float*)outp;
        outf[((size_t)n * 512 + OG + col) * HW + hw] = o0;
        outf[((size_t)n * 512 + OG + 16 + col) * HW + hw] = o1;
      } else {
        unsigned short* out16 = (unsigned short*)outp;
        out16[(size_t)px * 128 + OG + col] = f2bf(o0);
        out16[(size_t)px * 128 + OG + 16 + col] = f2bf(o1);
      }
    }
  }
}

// ---------------------------------------------------------------------------
extern "C" void kernel_launch(void* const* d_in, const int* in_sizes, int n_in,
                              void* d_out, int out_size, void* d_ws, size_t ws_size,
                              hipStream_t stream) {
  (void)in_sizes; (void)n_in; (void)out_size; (void)ws_size;
  const float* x = (const float*)d_in[0];
  const float* w1 = (const float*)d_in[1];
  const float* w2 = (const float*)d_in[2];
  const float* w3 = (const float*)d_in[3];
  const float* bn1g = (const float*)d_in[4];
  const float* bn1b = (const float*)d_in[5];
  const float* bn1m = (const float*)d_in[6];
  const float* bn1v = (const float*)d_in[7];
  const float* bn2g = (const float*)d_in[8];
  const float* bn2b = (const float*)d_in[9];
  const float* bn2m = (const float*)d_in[10];
  const float* bn2v = (const float*)d_in[11];
  const float* bn3g = (const float*)d_in[12];
  const float* bn3b = (const float*)d_in[13];
  const float* bn3m = (const float*)d_in[14];
  const float* bn3v = (const float*)d_in[15];

  unsigned short* ws = (unsigned short*)d_ws;
  unsigned short* zp = ws;                          // 256 shorts (zero page)
  unsigned short* w1d = ws + 256;                   // [128][1024]
  unsigned short* w2q = w1d + 128 * 1024;           // [128][1152]
  unsigned short* w3q = w2q + 128 * 1152;           // [512][128]
  unsigned short* a1 = w3q + 512 * 128;             // [50176][128]
  unsigned short* a2 = a1 + (size_t)PTOT * 128;     // [50176][128]
  // total ~26.4 MB

  hipMemsetAsync(zp, 0, 512, stream);

  wq1_kernel<<<8, 256, 0, stream>>>(w1, w1d);
  wq2_kernel<<<18, 256, 0, stream>>>(w2, w2q);
  wq3_kernel<<<8, 256, 0, stream>>>(w3, w3q);

  conv1_fused<<<dim3(PTOT / 64, 1), 256, 0, stream>>>(
      x, w1d, bn1g, bn1b, bn1m, bn1v, a1);
  gemm_bfp<1152, 1><<<dim3(PTOT / 64, 1), 256, 0, stream>>>(
      a1, w2q, bn2g, bn2b, bn2m, bn2v, nullptr, a2, zp);
  gemm_bfp<128, 2><<<dim3(PTOT / 64, 4), 256, 0, stream>>>(
      a2, w3q, bn3g, bn3b, bn3m, bn3v, x, d_out, zp);
}

// Round 5
// 396.143 us; speedup vs baseline: 2.1251x; 1.1145x over previous
//
#include <hip/hip_runtime.h>
#include <math.h>

// ---------------------------------------------------------------------------
// Round 5: conv3 epilogue vectorized (float4 resid loads + out stores,
// fully line-coalesced). Kernels split per-conv for profile attribution.
//   conv1_fused:  x NCHW fp32 -> hi/lo bf16 LDS -> K=1024 GEMM -> bfp -> a1
//   conv2_im2col: K=1152 (9 taps x 128c) GEMM -> bfp -> a2
//   conv3_res:    K=128 GEMM + bn3 + residual + relu + bfp -> out NCHW fp32
// ---------------------------------------------------------------------------

#define HW 784
#define WW 28
#define PTOT 50176   // 64*784

typedef short s8v __attribute__((ext_vector_type(8)));
typedef float f4v __attribute__((ext_vector_type(4)));

__device__ __forceinline__ f4v mfma16(s8v a, s8v b, f4v c) {
  return __builtin_amdgcn_mfma_f32_16x16x32_bf16(a, b, c, 0, 0, 0);
}

__device__ __forceinline__ unsigned short f2bf(float f) {
  unsigned u = __float_as_uint(f);
  u += 0x7fffu + ((u >> 16) & 1u);
  return (unsigned short)(u >> 16);
}
__device__ __forceinline__ float bf2f(unsigned short h) {
  return __uint_as_float(((unsigned)h) << 16);
}

// ---------------------------------------------------------------------------
// Weight quantization kernels -> bf16, [o][k] layouts
// ---------------------------------------------------------------------------
__global__ void wq1_kernel(const float* __restrict__ w, unsigned short* __restrict__ wd) {
  int task = blockIdx.x * blockDim.x + threadIdx.x;  // o(128) x cb(16)
  if (task >= 128 * 16) return;
  int cb = task & 15, o = task >> 4;
  const float* src = w + o * 512 + cb * 32;
  float vals[32], mx = 0.f;
#pragma unroll
  for (int j = 0; j < 32; ++j) { vals[j] = src[j]; mx = fmaxf(mx, fabsf(vals[j])); }
  float alpha = fmaxf(__fdiv_rn(mx, 127.0f), 1e-24f);
#pragma unroll
  for (int j = 0; j < 32; ++j) {
    unsigned short q = f2bf(__fmul_rn(rintf(__fdiv_rn(vals[j], alpha)), alpha));
    wd[o * 1024 + (cb * 32 + j) * 2] = q;      // hi slot
    wd[o * 1024 + (cb * 32 + j) * 2 + 1] = q;  // lo slot (same weight)
  }
}

__global__ void wq2_kernel(const float* __restrict__ w, unsigned short* __restrict__ wd) {
  int task = blockIdx.x * blockDim.x + threadIdx.x;  // o(128) x cb(4) x khw(9)
  if (task >= 128 * 36) return;
  int o = task / 36, rem = task % 36;
  int khw = rem % 9, cb = rem / 9;
  float vals[32], mx = 0.f;
#pragma unroll
  for (int j = 0; j < 32; ++j) {
    vals[j] = w[(o * 128 + cb * 32 + j) * 9 + khw];
    mx = fmaxf(mx, fabsf(vals[j]));
  }
  float alpha = fmaxf(__fdiv_rn(mx, 127.0f), 1e-24f);
#pragma unroll
  for (int j = 0; j < 32; ++j)
    wd[o * 1152 + khw * 128 + cb * 32 + j] =
        f2bf(__fmul_rn(rintf(__fdiv_rn(vals[j], alpha)), alpha));
}

__global__ void wq3_kernel(const float* __restrict__ w, unsigned short* __restrict__ wd) {
  int task = blockIdx.x * blockDim.x + threadIdx.x;  // o(512) x cb(4)
  if (task >= 512 * 4) return;
  int cb = task & 3, o = task >> 2;
  const float* src = w + o * 128 + cb * 32;
  float vals[32], mx = 0.f;
#pragma unroll
  for (int j = 0; j < 32; ++j) { vals[j] = src[j]; mx = fmaxf(mx, fabsf(vals[j])); }
  float alpha = fmaxf(__fdiv_rn(mx, 127.0f), 1e-24f);
#pragma unroll
  for (int j = 0; j < 32; ++j)
    wd[o * 128 + cb * 32 + j] = f2bf(__fmul_rn(rintf(__fdiv_rn(vals[j], alpha)), alpha));
}

// ---------------------------------------------------------------------------
// conv1 fused: x NCHW fp32 -> (hi/lo split in LDS) -> GEMM K=1024 ->
// bn1+relu+bfp -> a1 NHWC bf16. Block: 256 thr / 4 waves, 64 px x 128 o.
// ---------------------------------------------------------------------------
__global__ __launch_bounds__(256) void conv1_fused(
    const float* __restrict__ x, const unsigned short* __restrict__ Wq,
    const float* __restrict__ gg, const float* __restrict__ bb,
    const float* __restrict__ mm, const float* __restrict__ vv,
    unsigned short* __restrict__ out16) {
  __shared__ unsigned short As[64][72];  // 64 px x 64 kslots (+8 pad)

  const int t = threadIdx.x;
  const int w = t >> 6, l = t & 63;
  const int col = l & 15, row4 = l >> 4;
  const int P0 = blockIdx.x * 64;
  const int OG = w * 32;
  const int k0 = row4 * 8;

  const int p = P0 + l;
  const int n = p / HW;
  const int hw = p - n * HW;
  const float* xbase = x + (size_t)n * 512 * HW + hw;

  f4v acc[4][2];
#pragma unroll
  for (int pg = 0; pg < 4; ++pg)
#pragma unroll
    for (int og = 0; og < 2; ++og) acc[pg][og] = (f4v){0.f, 0.f, 0.f, 0.f};

  float xr[8];
#pragma unroll
  for (int j = 0; j < 8; ++j) xr[j] = xbase[(w * 8 + j) * HW];

  for (int s = 0; s < 16; ++s) {
    if (s) __syncthreads();  // previous stage's LDS reads complete
    // convert to hi/lo pairs and write 16 shorts (2 x b128)
    s8v sv0, sv1;
#pragma unroll
    for (int j = 0; j < 4; ++j) {
      unsigned short hi = f2bf(xr[j]);
      float lo = __fsub_rn(xr[j], bf2f(hi));
      sv0[2 * j] = (short)hi;
      sv0[2 * j + 1] = (short)f2bf(lo);
    }
#pragma unroll
    for (int j = 0; j < 4; ++j) {
      unsigned short hi = f2bf(xr[4 + j]);
      float lo = __fsub_rn(xr[4 + j], bf2f(hi));
      sv1[2 * j] = (short)hi;
      sv1[2 * j + 1] = (short)f2bf(lo);
    }
    *(s8v*)&As[l][w * 16] = sv0;
    *(s8v*)&As[l][w * 16 + 8] = sv1;
    __syncthreads();
    // prefetch next stage while this stage computes
    if (s < 15) {
#pragma unroll
      for (int j = 0; j < 8; ++j) xr[j] = xbase[((s + 1) * 32 + w * 8 + j) * HW];
    }
#pragma unroll
    for (int kk = 0; kk < 2; ++kk) {
      s8v b0 = *(const s8v*)(Wq + (size_t)(OG + col) * 1024 + s * 64 + kk * 32 + k0);
      s8v b1 = *(const s8v*)(Wq + (size_t)(OG + 16 + col) * 1024 + s * 64 + kk * 32 + k0);
#pragma unroll
      for (int pg = 0; pg < 4; ++pg) {
        s8v af = *(const s8v*)&As[pg * 16 + col][kk * 32 + k0];
        acc[pg][0] = mfma16(af, b0, acc[pg][0]);
        acc[pg][1] = mfma16(af, b1, acc[pg][1]);
      }
    }
  }

  // epilogue: bn + relu + bfp quant -> a1 NHWC bf16
  float inv_[2], ct_[2];
#pragma unroll
  for (int og = 0; og < 2; ++og) {
    int o = OG + og * 16 + col;
    float iv = __fdiv_rn(gg[o], sqrtf(__fadd_rn(vv[o], 1e-5f)));
    inv_[og] = iv;
    ct_[og] = __fsub_rn(bb[o], __fmul_rn(mm[o], iv));
  }
#pragma unroll
  for (int pg = 0; pg < 4; ++pg) {
#pragma unroll
    for (int r = 0; r < 4; ++r) {
      const int px = P0 + pg * 16 + row4 * 4 + r;
      float v0 = __fadd_rn(__fmul_rn(acc[pg][0][r], inv_[0]), ct_[0]);
      float v1 = __fadd_rn(__fmul_rn(acc[pg][1][r], inv_[1]), ct_[1]);
      v0 = fmaxf(v0, 0.f);
      v1 = fmaxf(v1, 0.f);
      float mx = fmaxf(v0, v1);
#pragma unroll
      for (int sfl = 1; sfl < 16; sfl <<= 1) mx = fmaxf(mx, __shfl_xor(mx, sfl));
      mx = fmaxf(mx, 1e-24f);
      int e = (int)(__float_as_uint(mx) >> 23) - 127;
      float dlt = __uint_as_float((unsigned)(e - 6 + 127) << 23);
      float idlt = __uint_as_float((unsigned)(6 - e + 127) << 23);
      float q0 = fminf(fmaxf(rintf(__fmul_rn(v0, idlt)), -128.f), 127.f);
      float q1 = fminf(fmaxf(rintf(__fmul_rn(v1, idlt)), -128.f), 127.f);
      out16[(size_t)px * 128 + OG + col] = f2bf(__fmul_rn(q0, dlt));
      out16[(size_t)px * 128 + OG + 16 + col] = f2bf(__fmul_rn(q1, dlt));
    }
  }
}

// ---------------------------------------------------------------------------
// conv2: 3x3 im2col GEMM K=1152, bf16 NHWC in/out.
// Block: 256 thr = 4 waves; tile 64 px x 128 o; wave = 64 px x 32 o.
// ---------------------------------------------------------------------------
__global__ __launch_bounds__(256) void conv2_im2col(
    const unsigned short* __restrict__ A, const unsigned short* __restrict__ Wq,
    const float* __restrict__ gg, const float* __restrict__ bb,
    const float* __restrict__ mm, const float* __restrict__ vv,
    unsigned short* __restrict__ out16, const unsigned short* __restrict__ zp) {
  const int t = threadIdx.x;
  const int w = t >> 6, l = t & 63;
  const int col = l & 15, row4 = l >> 4;
  const int P0 = blockIdx.x * 64;
  const int OG = w * 32;
  const int k0 = row4 * 8;

  const unsigned short* bbase[2];
#pragma unroll
  for (int og = 0; og < 2; ++og)
    bbase[og] = Wq + (size_t)(OG + og * 16 + col) * 1152 + k0;

  f4v acc[4][2];
#pragma unroll
  for (int pg = 0; pg < 4; ++pg)
#pragma unroll
    for (int og = 0; og < 2; ++og) acc[pg][og] = (f4v){0.f, 0.f, 0.f, 0.f};

  int hh[4], wl[4], nb[4];
#pragma unroll
  for (int pg = 0; pg < 4; ++pg) {
    int p = P0 + pg * 16 + col;
    int n = p / HW, hw = p - n * HW;
    hh[pg] = hw / WW;
    wl[pg] = hw - hh[pg] * WW;
    nb[pg] = n * HW;
  }
#pragma unroll
  for (int ty = 0; ty < 3; ++ty)
#pragma unroll
    for (int tx = 0; tx < 3; ++tx) {
      const int tap = ty * 3 + tx;
      const unsigned short* ab[4];
#pragma unroll
      for (int pg = 0; pg < 4; ++pg) {
        int h2 = hh[pg] + ty - 1, w2 = wl[pg] + tx - 1;
        bool ok = ((unsigned)h2 < 28u) & ((unsigned)w2 < 28u);
        ab[pg] = ok ? (A + (size_t)(nb[pg] + h2 * WW + w2) * 128 + k0) : (zp + k0);
      }
#pragma unroll
      for (int cb = 0; cb < 4; ++cb) {
        s8v bf0 = *(const s8v*)(bbase[0] + tap * 128 + cb * 32);
        s8v bf1 = *(const s8v*)(bbase[1] + tap * 128 + cb * 32);
#pragma unroll
        for (int pg = 0; pg < 4; ++pg) {
          s8v af = *(const s8v*)(ab[pg] + cb * 32);
          acc[pg][0] = mfma16(af, bf0, acc[pg][0]);
          acc[pg][1] = mfma16(af, bf1, acc[pg][1]);
        }
      }
    }

  float inv_[2], ct_[2];
#pragma unroll
  for (int og = 0; og < 2; ++og) {
    int o = OG + og * 16 + col;
    float iv = __fdiv_rn(gg[o], sqrtf(__fadd_rn(vv[o], 1e-5f)));
    inv_[og] = iv;
    ct_[og] = __fsub_rn(bb[o], __fmul_rn(mm[o], iv));
  }
#pragma unroll
  for (int pg = 0; pg < 4; ++pg) {
#pragma unroll
    for (int r = 0; r < 4; ++r) {
      const int px = P0 + pg * 16 + row4 * 4 + r;
      float v0 = __fadd_rn(__fmul_rn(acc[pg][0][r], inv_[0]), ct_[0]);
      float v1 = __fadd_rn(__fmul_rn(acc[pg][1][r], inv_[1]), ct_[1]);
      v0 = fmaxf(v0, 0.f);
      v1 = fmaxf(v1, 0.f);
      float mx = fmaxf(v0, v1);
#pragma unroll
      for (int sfl = 1; sfl < 16; sfl <<= 1) mx = fmaxf(mx, __shfl_xor(mx, sfl));
      mx = fmaxf(mx, 1e-24f);
      int e = (int)(__float_as_uint(mx) >> 23) - 127;
      float dlt = __uint_as_float((unsigned)(e - 6 + 127) << 23);
      float idlt = __uint_as_float((unsigned)(6 - e + 127) << 23);
      float q0 = fminf(fmaxf(rintf(__fmul_rn(v0, idlt)), -128.f), 127.f);
      float q1 = fminf(fmaxf(rintf(__fmul_rn(v1, idlt)), -128.f), 127.f);
      out16[(size_t)px * 128 + OG + col] = f2bf(__fmul_rn(q0, dlt));
      out16[(size_t)px * 128 + OG + 16 + col] = f2bf(__fmul_rn(q1, dlt));
    }
  }
}

// ---------------------------------------------------------------------------
// conv3: K=128 GEMM + bn3 + residual + relu + bfp -> out NCHW fp32.
// float4 resid loads / out stores: 4 consecutive px per thread (r index),
// lanes (row4) tile 64B lines -> fully coalesced.
// ---------------------------------------------------------------------------
__global__ __launch_bounds__(256) void conv3_res(
    const unsigned short* __restrict__ A, const unsigned short* __restrict__ Wq,
    const float* __restrict__ gg, const float* __restrict__ bb,
    const float* __restrict__ mm, const float* __restrict__ vv,
    const float* __restrict__ resid, float* __restrict__ outf) {
  const int t = threadIdx.x;
  const int w = t >> 6, l = t & 63;
  const int col = l & 15, row4 = l >> 4;
  const int P0 = blockIdx.x * 64;
  const int OG = blockIdx.y * 128 + w * 32;
  const int k0 = row4 * 8;

  const unsigned short* ab[4];
#pragma unroll
  for (int pg = 0; pg < 4; ++pg)
    ab[pg] = A + (size_t)(P0 + pg * 16 + col) * 128 + k0;
  const unsigned short* b0p = Wq + (size_t)(OG + col) * 128 + k0;
  const unsigned short* b1p = Wq + (size_t)(OG + 16 + col) * 128 + k0;

  f4v acc[4][2];
#pragma unroll
  for (int pg = 0; pg < 4; ++pg)
#pragma unroll
    for (int og = 0; og < 2; ++og) acc[pg][og] = (f4v){0.f, 0.f, 0.f, 0.f};

#pragma unroll
  for (int kb = 0; kb < 4; ++kb) {
    s8v bf0 = *(const s8v*)(b0p + kb * 32);
    s8v bf1 = *(const s8v*)(b1p + kb * 32);
#pragma unroll
    for (int pg = 0; pg < 4; ++pg) {
      s8v af = *(const s8v*)(ab[pg] + kb * 32);
      acc[pg][0] = mfma16(af, bf0, acc[pg][0]);
      acc[pg][1] = mfma16(af, bf1, acc[pg][1]);
    }
  }

  float inv_[2], ct_[2];
#pragma unroll
  for (int og = 0; og < 2; ++og) {
    int o = OG + og * 16 + col;
    float iv = __fdiv_rn(gg[o], sqrtf(__fadd_rn(vv[o], 1e-5f)));
    inv_[og] = iv;
    ct_[og] = __fsub_rn(bb[o], __fmul_rn(mm[o], iv));
  }

#pragma unroll
  for (int pg = 0; pg < 4; ++pg) {
    const int px0 = P0 + pg * 16 + row4 * 4;  // 4 consecutive px, 16B aligned
    const int n = px0 / HW;
    const int hw0 = px0 - n * HW;             // 784 % 16 == 0: no straddle
    const size_t base0 = ((size_t)n * 512 + OG + col) * HW + hw0;
    const size_t base1 = ((size_t)n * 512 + OG + 16 + col) * HW + hw0;
    const float4 r0 = *(const float4*)(resid + base0);
    const float4 r1 = *(const float4*)(resid + base1);
    const float rr0[4] = {r0.x, r0.y, r0.z, r0.w};
    const float rr1[4] = {r1.x, r1.y, r1.z, r1.w};
    float s0[4], s1[4];
#pragma unroll
    for (int r = 0; r < 4; ++r) {
      float v0 = __fadd_rn(__fmul_rn(acc[pg][0][r], inv_[0]), ct_[0]);
      float v1 = __fadd_rn(__fmul_rn(acc[pg][1][r], inv_[1]), ct_[1]);
      v0 = __fadd_rn(v0, rr0[r]);
      v1 = __fadd_rn(v1, rr1[r]);
      v0 = fmaxf(v0, 0.f);
      v1 = fmaxf(v1, 0.f);
      float mx = fmaxf(v0, v1);
#pragma unroll
      for (int sfl = 1; sfl < 16; sfl <<= 1) mx = fmaxf(mx, __shfl_xor(mx, sfl));
      mx = fmaxf(mx, 1e-24f);
      int e = (int)(__float_as_uint(mx) >> 23) - 127;
      float dlt = __uint_as_float((unsigned)(e - 6 + 127) << 23);
      float idlt = __uint_as_float((unsigned)(6 - e + 127) << 23);
      float q0 = fminf(fmaxf(rintf(__fmul_rn(v0, idlt)), -128.f), 127.f);
      float q1 = fminf(fmaxf(rintf(__fmul_rn(v1, idlt)), -128.f), 127.f);
      s0[r] = __fmul_rn(q0, dlt);
      s1[r] = __fmul_rn(q1, dlt);
    }
    *(float4*)(outf + base0) = make_float4(s0[0], s0[1], s0[2], s0[3]);
    *(float4*)(outf + base1) = make_float4(s1[0], s1[1], s1[2], s1[3]);
  }
}

// ---------------------------------------------------------------------------
extern "C" void kernel_launch(void* const* d_in, const int* in_sizes, int n_in,
                              void* d_out, int out_size, void* d_ws, size_t ws_size,
                              hipStream_t stream) {
  (void)in_sizes; (void)n_in; (void)out_size; (void)ws_size;
  const float* x = (const float*)d_in[0];
  const float* w1 = (const float*)d_in[1];
  const float* w2 = (const float*)d_in[2];
  const float* w3 = (const float*)d_in[3];
  const float* bn1g = (const float*)d_in[4];
  const float* bn1b = (const float*)d_in[5];
  const float* bn1m = (const float*)d_in[6];
  const float* bn1v = (const float*)d_in[7];
  const float* bn2g = (const float*)d_in[8];
  const float* bn2b = (const float*)d_in[9];
  const float* bn2m = (const float*)d_in[10];
  const float* bn2v = (const float*)d_in[11];
  const float* bn3g = (const float*)d_in[12];
  const float* bn3b = (const float*)d_in[13];
  const float* bn3m = (const float*)d_in[14];
  const float* bn3v = (const float*)d_in[15];

  unsigned short* ws = (unsigned short*)d_ws;
  unsigned short* zp = ws;                          // 256 shorts (zero page)
  unsigned short* w1d = ws + 256;                   // [128][1024]
  unsigned short* w2q = w1d + 128 * 1024;           // [128][1152]
  unsigned short* w3q = w2q + 128 * 1152;           // [512][128]
  unsigned short* a1 = w3q + 512 * 128;             // [50176][128]
  unsigned short* a2 = a1 + (size_t)PTOT * 128;     // [50176][128]
  // total ~26.4 MB

  hipMemsetAsync(zp, 0, 512, stream);

  wq1_kernel<<<8, 256, 0, stream>>>(w1, w1d);
  wq2_kernel<<<18, 256, 0, stream>>>(w2, w2q);
  wq3_kernel<<<8, 256, 0, stream>>>(w3, w3q);

  conv1_fused<<<dim3(PTOT / 64, 1), 256, 0, stream>>>(
      x, w1d, bn1g, bn1b, bn1m, bn1v, a1);
  conv2_im2col<<<dim3(PTOT / 64, 1), 256, 0, stream>>>(
      a1, w2q, bn2g, bn2b, bn2m, bn2v, a2, zp);
  conv3_res<<<dim3(PTOT / 64, 4), 256, 0, stream>>>(
      a2, w3q, bn3g, bn3b, bn3m, bn3v, x, (float*)d_out);
}

// Round 6
// 380.611 us; speedup vs baseline: 2.2118x; 1.0408x over previous
//
#include <hip/hip_runtime.h>
#include <math.h>

// ---------------------------------------------------------------------------
// Round 6: conv2 software-pipelined (1-step prefetch, reg cap 170, XCD swizzle)
//          conv1 LDS double-buffered (1 barrier/stage), reg cap 170.
//   conv1_fused:  x NCHW fp32 -> hi/lo bf16 LDS -> K=1024 GEMM -> bfp -> a1
//   conv2_im2col: K=1152 (9 taps x 128c) GEMM -> bfp -> a2
//   conv3_res:    K=128 GEMM + bn3 + residual + relu + bfp -> out NCHW fp32
// ---------------------------------------------------------------------------

#define HW 784
#define WW 28
#define PTOT 50176   // 64*784

typedef short s8v __attribute__((ext_vector_type(8)));
typedef float f4v __attribute__((ext_vector_type(4)));

__device__ __forceinline__ f4v mfma16(s8v a, s8v b, f4v c) {
  return __builtin_amdgcn_mfma_f32_16x16x32_bf16(a, b, c, 0, 0, 0);
}

__device__ __forceinline__ unsigned short f2bf(float f) {
  unsigned u = __float_as_uint(f);
  u += 0x7fffu + ((u >> 16) & 1u);
  return (unsigned short)(u >> 16);
}
__device__ __forceinline__ float bf2f(unsigned short h) {
  return __uint_as_float(((unsigned)h) << 16);
}

// ---------------------------------------------------------------------------
// Weight quantization kernels -> bf16, [o][k] layouts
// ---------------------------------------------------------------------------
__global__ void wq1_kernel(const float* __restrict__ w, unsigned short* __restrict__ wd) {
  int task = blockIdx.x * blockDim.x + threadIdx.x;  // o(128) x cb(16)
  if (task >= 128 * 16) return;
  int cb = task & 15, o = task >> 4;
  const float* src = w + o * 512 + cb * 32;
  float vals[32], mx = 0.f;
#pragma unroll
  for (int j = 0; j < 32; ++j) { vals[j] = src[j]; mx = fmaxf(mx, fabsf(vals[j])); }
  float alpha = fmaxf(__fdiv_rn(mx, 127.0f), 1e-24f);
#pragma unroll
  for (int j = 0; j < 32; ++j) {
    unsigned short q = f2bf(__fmul_rn(rintf(__fdiv_rn(vals[j], alpha)), alpha));
    wd[o * 1024 + (cb * 32 + j) * 2] = q;      // hi slot
    wd[o * 1024 + (cb * 32 + j) * 2 + 1] = q;  // lo slot (same weight)
  }
}

__global__ void wq2_kernel(const float* __restrict__ w, unsigned short* __restrict__ wd) {
  int task = blockIdx.x * blockDim.x + threadIdx.x;  // o(128) x cb(4) x khw(9)
  if (task >= 128 * 36) return;
  int o = task / 36, rem = task % 36;
  int khw = rem % 9, cb = rem / 9;
  float vals[32], mx = 0.f;
#pragma unroll
  for (int j = 0; j < 32; ++j) {
    vals[j] = w[(o * 128 + cb * 32 + j) * 9 + khw];
    mx = fmaxf(mx, fabsf(vals[j]));
  }
  float alpha = fmaxf(__fdiv_rn(mx, 127.0f), 1e-24f);
#pragma unroll
  for (int j = 0; j < 32; ++j)
    wd[o * 1152 + khw * 128 + cb * 32 + j] =
        f2bf(__fmul_rn(rintf(__fdiv_rn(vals[j], alpha)), alpha));
}

__global__ void wq3_kernel(const float* __restrict__ w, unsigned short* __restrict__ wd) {
  int task = blockIdx.x * blockDim.x + threadIdx.x;  // o(512) x cb(4)
  if (task >= 512 * 4) return;
  int cb = task & 3, o = task >> 2;
  const float* src = w + o * 128 + cb * 32;
  float vals[32], mx = 0.f;
#pragma unroll
  for (int j = 0; j < 32; ++j) { vals[j] = src[j]; mx = fmaxf(mx, fabsf(vals[j])); }
  float alpha = fmaxf(__fdiv_rn(mx, 127.0f), 1e-24f);
#pragma unroll
  for (int j = 0; j < 32; ++j)
    wd[o * 128 + cb * 32 + j] = f2bf(__fmul_rn(rintf(__fdiv_rn(vals[j], alpha)), alpha));
}

// ---------------------------------------------------------------------------
// conv1 fused: x NCHW fp32 -> (hi/lo split, double-buffered LDS) -> K=1024
// GEMM -> bn1+relu+bfp -> a1 NHWC bf16. 256 thr / 4 waves, 64 px x 128 o.
// ---------------------------------------------------------------------------
__global__ __launch_bounds__(256, 3) void conv1_fused(
    const float* __restrict__ x, const unsigned short* __restrict__ Wq,
    const float* __restrict__ gg, const float* __restrict__ bb,
    const float* __restrict__ mm, const float* __restrict__ vv,
    unsigned short* __restrict__ out16) {
  __shared__ unsigned short As[2][64][72];  // double buffer, +8 pad

  const int t = threadIdx.x;
  const int w = t >> 6, l = t & 63;
  const int col = l & 15, row4 = l >> 4;
  const int P0 = blockIdx.x * 64;
  const int OG = w * 32;
  const int k0 = row4 * 8;

  const int p = P0 + l;
  const int n = p / HW;
  const int hw = p - n * HW;
  const float* xbase = x + (size_t)n * 512 * HW + hw;

  f4v acc[4][2];
#pragma unroll
  for (int pg = 0; pg < 4; ++pg)
#pragma unroll
    for (int og = 0; og < 2; ++og) acc[pg][og] = (f4v){0.f, 0.f, 0.f, 0.f};

  float xr[8];
#pragma unroll
  for (int j = 0; j < 8; ++j) xr[j] = xbase[(w * 8 + j) * HW];

#pragma unroll 2
  for (int s = 0; s < 16; ++s) {
    // convert to hi/lo pairs and write 16 shorts (2 x b128) to buf s&1
    s8v sv0, sv1;
#pragma unroll
    for (int j = 0; j < 4; ++j) {
      unsigned short hi = f2bf(xr[j]);
      float lo = __fsub_rn(xr[j], bf2f(hi));
      sv0[2 * j] = (short)hi;
      sv0[2 * j + 1] = (short)f2bf(lo);
    }
#pragma unroll
    for (int j = 0; j < 4; ++j) {
      unsigned short hi = f2bf(xr[4 + j]);
      float lo = __fsub_rn(xr[4 + j], bf2f(hi));
      sv1[2 * j] = (short)hi;
      sv1[2 * j + 1] = (short)f2bf(lo);
    }
    *(s8v*)&As[s & 1][l][w * 16] = sv0;
    *(s8v*)&As[s & 1][l][w * 16 + 8] = sv1;
    __syncthreads();  // writes of buf[s&1] done; prior reads of buf[s&1] (s-2)
                      // completed at barrier s-1 -> safe
    // prefetch next stage while this stage computes
    if (s < 15) {
#pragma unroll
      for (int j = 0; j < 8; ++j) xr[j] = xbase[((s + 1) * 32 + w * 8 + j) * HW];
    }
#pragma unroll
    for (int kk = 0; kk < 2; ++kk) {
      s8v b0 = *(const s8v*)(Wq + (size_t)(OG + col) * 1024 + s * 64 + kk * 32 + k0);
      s8v b1 = *(const s8v*)(Wq + (size_t)(OG + 16 + col) * 1024 + s * 64 + kk * 32 + k0);
#pragma unroll
      for (int pg = 0; pg < 4; ++pg) {
        s8v af = *(const s8v*)&As[s & 1][pg * 16 + col][kk * 32 + k0];
        acc[pg][0] = mfma16(af, b0, acc[pg][0]);
        acc[pg][1] = mfma16(af, b1, acc[pg][1]);
      }
    }
  }

  // epilogue: bn + relu + bfp quant -> a1 NHWC bf16
  float inv_[2], ct_[2];
#pragma unroll
  for (int og = 0; og < 2; ++og) {
    int o = OG + og * 16 + col;
    float iv = __fdiv_rn(gg[o], sqrtf(__fadd_rn(vv[o], 1e-5f)));
    inv_[og] = iv;
    ct_[og] = __fsub_rn(bb[o], __fmul_rn(mm[o], iv));
  }
#pragma unroll
  for (int pg = 0; pg < 4; ++pg) {
#pragma unroll
    for (int r = 0; r < 4; ++r) {
      const int px = P0 + pg * 16 + row4 * 4 + r;
      float v0 = __fadd_rn(__fmul_rn(acc[pg][0][r], inv_[0]), ct_[0]);
      float v1 = __fadd_rn(__fmul_rn(acc[pg][1][r], inv_[1]), ct_[1]);
      v0 = fmaxf(v0, 0.f);
      v1 = fmaxf(v1, 0.f);
      float mx = fmaxf(v0, v1);
#pragma unroll
      for (int sfl = 1; sfl < 16; sfl <<= 1) mx = fmaxf(mx, __shfl_xor(mx, sfl));
      mx = fmaxf(mx, 1e-24f);
      int e = (int)(__float_as_uint(mx) >> 23) - 127;
      float dlt = __uint_as_float((unsigned)(e - 6 + 127) << 23);
      float idlt = __uint_as_float((unsigned)(6 - e + 127) << 23);
      float q0 = fminf(fmaxf(rintf(__fmul_rn(v0, idlt)), -128.f), 127.f);
      float q1 = fminf(fmaxf(rintf(__fmul_rn(v1, idlt)), -128.f), 127.f);
      out16[(size_t)px * 128 + OG + col] = f2bf(__fmul_rn(q0, dlt));
      out16[(size_t)px * 128 + OG + 16 + col] = f2bf(__fmul_rn(q1, dlt));
    }
  }
}

// ---------------------------------------------------------------------------
// conv2: 3x3 im2col GEMM K=1152. Software-pipelined (1-step prefetch),
// XCD-swizzled blocks (784 = 8 x 98; 98 blocks = exactly 8 images per XCD).
// ---------------------------------------------------------------------------
#define C2_SETTAP(ty_, tx_)                                                  \
  {                                                                          \
    _Pragma("unroll") for (int pg = 0; pg < 4; ++pg) {                       \
      int h2 = hh[pg] + (ty_)-1, w2 = wl[pg] + (tx_)-1;                      \
      bool ok = ((unsigned)h2 < 28u) & ((unsigned)w2 < 28u);                 \
      ap[pg] = ok ? (A + (size_t)(nb[pg] + h2 * WW + w2) * 128 + k0)         \
                  : (zp + k0);                                               \
    }                                                                        \
  }

#define C2_LOAD(Ab, Bb0, Bb1, s_)                                            \
  {                                                                          \
    const int tap_ = (s_) >> 2, cb_ = (s_)&3;                                \
    if (cb_ == 0) C2_SETTAP(tap_ / 3, tap_ % 3);                             \
    Bb0 = *(const s8v*)(bb0 + tap_ * 128 + cb_ * 32);                        \
    Bb1 = *(const s8v*)(bb1 + tap_ * 128 + cb_ * 32);                        \
    _Pragma("unroll") for (int pg = 0; pg < 4; ++pg)                         \
        Ab[pg] = *(const s8v*)(ap[pg] + cb_ * 32);                           \
  }

#define C2_MFMA(Ab, Bb0, Bb1)                                                \
  {                                                                          \
    _Pragma("unroll") for (int pg = 0; pg < 4; ++pg) {                       \
      acc[pg][0] = mfma16(Ab[pg], Bb0, acc[pg][0]);                          \
      acc[pg][1] = mfma16(Ab[pg], Bb1, acc[pg][1]);                          \
    }                                                                        \
  }

__global__ __launch_bounds__(256, 3) void conv2_im2col(
    const unsigned short* __restrict__ A, const unsigned short* __restrict__ Wq,
    const float* __restrict__ gg, const float* __restrict__ bb,
    const float* __restrict__ mm, const float* __restrict__ vv,
    unsigned short* __restrict__ out16, const unsigned short* __restrict__ zp) {
  const int t = threadIdx.x;
  const int w = t >> 6, l = t & 63;
  const int col = l & 15, row4 = l >> 4;
  // bijective XCD swizzle: XCD k owns images 8k..8k+7 (a1 slice L2-resident)
  const int bid = blockIdx.x;
  const int P0 = ((bid & 7) * 98 + (bid >> 3)) * 64;
  const int OG = w * 32;
  const int k0 = row4 * 8;

  const unsigned short* bb0 = Wq + (size_t)(OG + col) * 1152 + k0;
  const unsigned short* bb1 = Wq + (size_t)(OG + 16 + col) * 1152 + k0;

  f4v acc[4][2];
#pragma unroll
  for (int pg = 0; pg < 4; ++pg)
#pragma unroll
    for (int og = 0; og < 2; ++og) acc[pg][og] = (f4v){0.f, 0.f, 0.f, 0.f};

  int hh[4], wl[4], nb[4];
#pragma unroll
  for (int pg = 0; pg < 4; ++pg) {
    int p = P0 + pg * 16 + col;
    int n = p / HW, hw = p - n * HW;
    hh[pg] = hw / WW;
    wl[pg] = hw - hh[pg] * WW;
    nb[pg] = n * HW;
  }

  const unsigned short* ap[4];
  s8v A0[4], A1[4], B00, B01, B10, B11;
  C2_LOAD(A0, B00, B01, 0);
#pragma unroll
  for (int ss = 0; ss < 18; ++ss) {
    C2_LOAD(A1, B10, B11, 2 * ss + 1);
    C2_MFMA(A0, B00, B01);
    if (ss < 17) C2_LOAD(A0, B00, B01, 2 * ss + 2);
    C2_MFMA(A1, B10, B11);
  }

  float inv_[2], ct_[2];
#pragma unroll
  for (int og = 0; og < 2; ++og) {
    int o = OG + og * 16 + col;
    float iv = __fdiv_rn(gg[o], sqrtf(__fadd_rn(vv[o], 1e-5f)));
    inv_[og] = iv;
    ct_[og] = __fsub_rn(bb[o], __fmul_rn(mm[o], iv));
  }
#pragma unroll
  for (int pg = 0; pg < 4; ++pg) {
#pragma unroll
    for (int r = 0; r < 4; ++r) {
      const int px = P0 + pg * 16 + row4 * 4 + r;
      float v0 = __fadd_rn(__fmul_rn(acc[pg][0][r], inv_[0]), ct_[0]);
      float v1 = __fadd_rn(__fmul_rn(acc[pg][1][r], inv_[1]), ct_[1]);
      v0 = fmaxf(v0, 0.f);
      v1 = fmaxf(v1, 0.f);
      float mx = fmaxf(v0, v1);
#pragma unroll
      for (int sfl = 1; sfl < 16; sfl <<= 1) mx = fmaxf(mx, __shfl_xor(mx, sfl));
      mx = fmaxf(mx, 1e-24f);
      int e = (int)(__float_as_uint(mx) >> 23) - 127;
      float dlt = __uint_as_float((unsigned)(e - 6 + 127) << 23);
      float idlt = __uint_as_float((unsigned)(6 - e + 127) << 23);
      float q0 = fminf(fmaxf(rintf(__fmul_rn(v0, idlt)), -128.f), 127.f);
      float q1 = fminf(fmaxf(rintf(__fmul_rn(v1, idlt)), -128.f), 127.f);
      out16[(size_t)px * 128 + OG + col] = f2bf(__fmul_rn(q0, dlt));
      out16[(size_t)px * 128 + OG + 16 + col] = f2bf(__fmul_rn(q1, dlt));
    }
  }
}

// ---------------------------------------------------------------------------
// conv3: K=128 GEMM + bn3 + residual + relu + bfp -> out NCHW fp32.
// float4 resid loads / out stores (line-coalesced).
// ---------------------------------------------------------------------------
__global__ __launch_bounds__(256) void conv3_res(
    const unsigned short* __restrict__ A, const unsigned short* __restrict__ Wq,
    const float* __restrict__ gg, const float* __restrict__ bb,
    const float* __restrict__ mm, const float* __restrict__ vv,
    const float* __restrict__ resid, float* __restrict__ outf) {
  const int t = threadIdx.x;
  const int w = t >> 6, l = t & 63;
  const int col = l & 15, row4 = l >> 4;
  const int P0 = blockIdx.x * 64;
  const int OG = blockIdx.y * 128 + w * 32;
  const int k0 = row4 * 8;

  const unsigned short* ab[4];
#pragma unroll
  for (int pg = 0; pg < 4; ++pg)
    ab[pg] = A + (size_t)(P0 + pg * 16 + col) * 128 + k0;
  const unsigned short* b0p = Wq + (size_t)(OG + col) * 128 + k0;
  const unsigned short* b1p = Wq + (size_t)(OG + 16 + col) * 128 + k0;

  f4v acc[4][2];
#pragma unroll
  for (int pg = 0; pg < 4; ++pg)
#pragma unroll
    for (int og = 0; og < 2; ++og) acc[pg][og] = (f4v){0.f, 0.f, 0.f, 0.f};

#pragma unroll
  for (int kb = 0; kb < 4; ++kb) {
    s8v bf0 = *(const s8v*)(b0p + kb * 32);
    s8v bf1 = *(const s8v*)(b1p + kb * 32);
#pragma unroll
    for (int pg = 0; pg < 4; ++pg) {
      s8v af = *(const s8v*)(ab[pg] + kb * 32);
      acc[pg][0] = mfma16(af, bf0, acc[pg][0]);
      acc[pg][1] = mfma16(af, bf1, acc[pg][1]);
    }
  }

  float inv_[2], ct_[2];
#pragma unroll
  for (int og = 0; og < 2; ++og) {
    int o = OG + og * 16 + col;
    float iv = __fdiv_rn(gg[o], sqrtf(__fadd_rn(vv[o], 1e-5f)));
    inv_[og] = iv;
    ct_[og] = __fsub_rn(bb[o], __fmul_rn(mm[o], iv));
  }

#pragma unroll
  for (int pg = 0; pg < 4; ++pg) {
    const int px0 = P0 + pg * 16 + row4 * 4;  // 4 consecutive px, 16B aligned
    const int n = px0 / HW;
    const int hw0 = px0 - n * HW;             // 784 % 16 == 0: no straddle
    const size_t base0 = ((size_t)n * 512 + OG + col) * HW + hw0;
    const size_t base1 = ((size_t)n * 512 + OG + 16 + col) * HW + hw0;
    const float4 r0 = *(const float4*)(resid + base0);
    const float4 r1 = *(const float4*)(resid + base1);
    const float rr0[4] = {r0.x, r0.y, r0.z, r0.w};
    const float rr1[4] = {r1.x, r1.y, r1.z, r1.w};
    float s0[4], s1[4];
#pragma unroll
    for (int r = 0; r < 4; ++r) {
      float v0 = __fadd_rn(__fmul_rn(acc[pg][0][r], inv_[0]), ct_[0]);
      float v1 = __fadd_rn(__fmul_rn(acc[pg][1][r], inv_[1]), ct_[1]);
      v0 = __fadd_rn(v0, rr0[r]);
      v1 = __fadd_rn(v1, rr1[r]);
      v0 = fmaxf(v0, 0.f);
      v1 = fmaxf(v1, 0.f);
      float mx = fmaxf(v0, v1);
#pragma unroll
      for (int sfl = 1; sfl < 16; sfl <<= 1) mx = fmaxf(mx, __shfl_xor(mx, sfl));
      mx = fmaxf(mx, 1e-24f);
      int e = (int)(__float_as_uint(mx) >> 23) - 127;
      float dlt = __uint_as_float((unsigned)(e - 6 + 127) << 23);
      float idlt = __uint_as_float((unsigned)(6 - e + 127) << 23);
      float q0 = fminf(fmaxf(rintf(__fmul_rn(v0, idlt)), -128.f), 127.f);
      float q1 = fminf(fmaxf(rintf(__fmul_rn(v1, idlt)), -128.f), 127.f);
      s0[r] = __fmul_rn(q0, dlt);
      s1[r] = __fmul_rn(q1, dlt);
    }
    *(float4*)(outf + base0) = make_float4(s0[0], s0[1], s0[2], s0[3]);
    *(float4*)(outf + base1) = make_float4(s1[0], s1[1], s1[2], s1[3]);
  }
}

// ---------------------------------------------------------------------------
extern "C" void kernel_launch(void* const* d_in, const int* in_sizes, int n_in,
                              void* d_out, int out_size, void* d_ws, size_t ws_size,
                              hipStream_t stream) {
  (void)in_sizes; (void)n_in; (void)out_size; (void)ws_size;
  const float* x = (const float*)d_in[0];
  const float* w1 = (const float*)d_in[1];
  const float* w2 = (const float*)d_in[2];
  const float* w3 = (const float*)d_in[3];
  const float* bn1g = (const float*)d_in[4];
  const float* bn1b = (const float*)d_in[5];
  const float* bn1m = (const float*)d_in[6];
  const float* bn1v = (const float*)d_in[7];
  const float* bn2g = (const float*)d_in[8];
  const float* bn2b = (const float*)d_in[9];
  const float* bn2m = (const float*)d_in[10];
  const float* bn2v = (const float*)d_in[11];
  const float* bn3g = (const float*)d_in[12];
  const float* bn3b = (const float*)d_in[13];
  const float* bn3m = (const float*)d_in[14];
  const float* bn3v = (const float*)d_in[15];

  unsigned short* ws = (unsigned short*)d_ws;
  unsigned short* zp = ws;                          // 256 shorts (zero page)
  unsigned short* w1d = ws + 256;                   // [128][1024]
  unsigned short* w2q = w1d + 128 * 1024;           // [128][1152]
  unsigned short* w3q = w2q + 128 * 1152;           // [512][128]
  unsigned short* a1 = w3q + 512 * 128;             // [50176][128]
  unsigned short* a2 = a1 + (size_t)PTOT * 128;     // [50176][128]
  // total ~26.4 MB

  hipMemsetAsync(zp, 0, 512, stream);

  wq1_kernel<<<8, 256, 0, stream>>>(w1, w1d);
  wq2_kernel<<<18, 256, 0, stream>>>(w2, w2q);
  wq3_kernel<<<8, 256, 0, stream>>>(w3, w3q);

  conv1_fused<<<dim3(PTOT / 64, 1), 256, 0, stream>>>(
      x, w1d, bn1g, bn1b, bn1m, bn1v, a1);
  conv2_im2col<<<dim3(PTOT / 64, 1), 256, 0, stream>>>(
      a1, w2q, bn2g, bn2b, bn2m, bn2v, a2, zp);
  conv3_res<<<dim3(PTOT / 64, 4), 256, 0, stream>>>(
      a2, w3q, bn3g, bn3b, bn3m, bn3v, x, (float*)d_out);
}

// Round 9
// 343.241 us; speedup vs baseline: 2.4526x; 1.1089x over previous
//
#include <hip/hip_runtime.h>
#include <math.h>

// ---------------------------------------------------------------------------
// Round 9 (Round-7 code, 3rd submit; rounds 7/8 hit GPU-acquisition timeouts):
//   conv2 on 2-phase LDS template: per 3x3 tap async global_load_lds A-tile
//   (64px x 128ch, dbuf, chunk-XOR swizzled) + reg-prefetch next tap's B;
//   barrier drains both; 32 MFMAs per phase. XCD-swizzled blockIdx.
//   conv1_fused:  x NCHW fp32 -> hi/lo bf16 LDS -> K=1024 GEMM -> bfp -> a1
//   conv2_im2col: K=1152 (9 taps x 128c) GEMM -> bfp -> a2
//   conv3_res:    K=128 GEMM + bn3 + residual + relu + bfp -> out NCHW fp32
// ---------------------------------------------------------------------------

#define HW 784
#define WW 28
#define PTOT 50176   // 64*784

typedef short s8v __attribute__((ext_vector_type(8)));
typedef float f4v __attribute__((ext_vector_type(4)));

__device__ __forceinline__ f4v mfma16(s8v a, s8v b, f4v c) {
  return __builtin_amdgcn_mfma_f32_16x16x32_bf16(a, b, c, 0, 0, 0);
}

__device__ __forceinline__ unsigned short f2bf(float f) {
  unsigned u = __float_as_uint(f);
  u += 0x7fffu + ((u >> 16) & 1u);
  return (unsigned short)(u >> 16);
}
__device__ __forceinline__ float bf2f(unsigned short h) {
  return __uint_as_float(((unsigned)h) << 16);
}

// async 16B global -> LDS (dest: wave-uniform base + lane*16)
__device__ __forceinline__ void gload_lds16(const void* g, void* l) {
  __builtin_amdgcn_global_load_lds(
      (const __attribute__((address_space(1))) unsigned*)g,
      (__attribute__((address_space(3))) unsigned*)l, 16, 0, 0);
}

// ---------------------------------------------------------------------------
// Weight quantization kernels -> bf16, [o][k] layouts
// ---------------------------------------------------------------------------
__global__ void wq1_kernel(const float* __restrict__ w, unsigned short* __restrict__ wd) {
  int task = blockIdx.x * blockDim.x + threadIdx.x;  // o(128) x cb(16)
  if (task >= 128 * 16) return;
  int cb = task & 15, o = task >> 4;
  const float* src = w + o * 512 + cb * 32;
  float vals[32], mx = 0.f;
#pragma unroll
  for (int j = 0; j < 32; ++j) { vals[j] = src[j]; mx = fmaxf(mx, fabsf(vals[j])); }
  float alpha = fmaxf(__fdiv_rn(mx, 127.0f), 1e-24f);
#pragma unroll
  for (int j = 0; j < 32; ++j) {
    unsigned short q = f2bf(__fmul_rn(rintf(__fdiv_rn(vals[j], alpha)), alpha));
    wd[o * 1024 + (cb * 32 + j) * 2] = q;      // hi slot
    wd[o * 1024 + (cb * 32 + j) * 2 + 1] = q;  // lo slot (same weight)
  }
}

__global__ void wq2_kernel(const float* __restrict__ w, unsigned short* __restrict__ wd) {
  int task = blockIdx.x * blockDim.x + threadIdx.x;  // o(128) x cb(4) x khw(9)
  if (task >= 128 * 36) return;
  int o = task / 36, rem = task % 36;
  int khw = rem % 9, cb = rem / 9;
  float vals[32], mx = 0.f;
#pragma unroll
  for (int j = 0; j < 32; ++j) {
    vals[j] = w[(o * 128 + cb * 32 + j) * 9 + khw];
    mx = fmaxf(mx, fabsf(vals[j]));
  }
  float alpha = fmaxf(__fdiv_rn(mx, 127.0f), 1e-24f);
#pragma unroll
  for (int j = 0; j < 32; ++j)
    wd[o * 1152 + khw * 128 + cb * 32 + j] =
        f2bf(__fmul_rn(rintf(__fdiv_rn(vals[j], alpha)), alpha));
}

__global__ void wq3_kernel(const float* __restrict__ w, unsigned short* __restrict__ wd) {
  int task = blockIdx.x * blockDim.x + threadIdx.x;  // o(512) x cb(4)
  if (task >= 512 * 4) return;
  int cb = task & 3, o = task >> 2;
  const float* src = w + o * 128 + cb * 32;
  float vals[32], mx = 0.f;
#pragma unroll
  for (int j = 0; j < 32; ++j) { vals[j] = src[j]; mx = fmaxf(mx, fabsf(vals[j])); }
  float alpha = fmaxf(__fdiv_rn(mx, 127.0f), 1e-24f);
#pragma unroll
  for (int j = 0; j < 32; ++j)
    wd[o * 128 + cb * 32 + j] = f2bf(__fmul_rn(rintf(__fdiv_rn(vals[j], alpha)), alpha));
}

// ---------------------------------------------------------------------------
// conv1 fused: x NCHW fp32 -> (hi/lo split, double-buffered LDS) -> K=1024
// GEMM -> bn1+relu+bfp -> a1 NHWC bf16. 256 thr / 4 waves, 64 px x 128 o.
// ---------------------------------------------------------------------------
__global__ __launch_bounds__(256, 3) void conv1_fused(
    const float* __restrict__ x, const unsigned short* __restrict__ Wq,
    const float* __restrict__ gg, const float* __restrict__ bb,
    const float* __restrict__ mm, const float* __restrict__ vv,
    unsigned short* __restrict__ out16) {
  __shared__ unsigned short As[2][64][72];  // double buffer, +8 pad

  const int t = threadIdx.x;
  const int w = t >> 6, l = t & 63;
  const int col = l & 15, row4 = l >> 4;
  const int P0 = blockIdx.x * 64;
  const int OG = w * 32;
  const int k0 = row4 * 8;

  const int p = P0 + l;
  const int n = p / HW;
  const int hw = p - n * HW;
  const float* xbase = x + (size_t)n * 512 * HW + hw;

  f4v acc[4][2];
#pragma unroll
  for (int pg = 0; pg < 4; ++pg)
#pragma unroll
    for (int og = 0; og < 2; ++og) acc[pg][og] = (f4v){0.f, 0.f, 0.f, 0.f};

  float xr[8];
#pragma unroll
  for (int j = 0; j < 8; ++j) xr[j] = xbase[(w * 8 + j) * HW];

#pragma unroll 2
  for (int s = 0; s < 16; ++s) {
    // convert to hi/lo pairs and write 16 shorts (2 x b128) to buf s&1
    s8v sv0, sv1;
#pragma unroll
    for (int j = 0; j < 4; ++j) {
      unsigned short hi = f2bf(xr[j]);
      float lo = __fsub_rn(xr[j], bf2f(hi));
      sv0[2 * j] = (short)hi;
      sv0[2 * j + 1] = (short)f2bf(lo);
    }
#pragma unroll
    for (int j = 0; j < 4; ++j) {
      unsigned short hi = f2bf(xr[4 + j]);
      float lo = __fsub_rn(xr[4 + j], bf2f(hi));
      sv1[2 * j] = (short)hi;
      sv1[2 * j + 1] = (short)f2bf(lo);
    }
    *(s8v*)&As[s & 1][l][w * 16] = sv0;
    *(s8v*)&As[s & 1][l][w * 16 + 8] = sv1;
    __syncthreads();  // writes of buf[s&1] done; prior reads of buf[s&1] (s-2)
                      // completed at barrier s-1 -> safe
    // prefetch next stage while this stage computes
    if (s < 15) {
#pragma unroll
      for (int j = 0; j < 8; ++j) xr[j] = xbase[((s + 1) * 32 + w * 8 + j) * HW];
    }
#pragma unroll
    for (int kk = 0; kk < 2; ++kk) {
      s8v b0 = *(const s8v*)(Wq + (size_t)(OG + col) * 1024 + s * 64 + kk * 32 + k0);
      s8v b1 = *(const s8v*)(Wq + (size_t)(OG + 16 + col) * 1024 + s * 64 + kk * 32 + k0);
#pragma unroll
      for (int pg = 0; pg < 4; ++pg) {
        s8v af = *(const s8v*)&As[s & 1][pg * 16 + col][kk * 32 + k0];
        acc[pg][0] = mfma16(af, b0, acc[pg][0]);
        acc[pg][1] = mfma16(af, b1, acc[pg][1]);
      }
    }
  }

  // epilogue: bn + relu + bfp quant -> a1 NHWC bf16
  float inv_[2], ct_[2];
#pragma unroll
  for (int og = 0; og < 2; ++og) {
    int o = OG + og * 16 + col;
    float iv = __fdiv_rn(gg[o], sqrtf(__fadd_rn(vv[o], 1e-5f)));
    inv_[og] = iv;
    ct_[og] = __fsub_rn(bb[o], __fmul_rn(mm[o], iv));
  }
#pragma unroll
  for (int pg = 0; pg < 4; ++pg) {
#pragma unroll
    for (int r = 0; r < 4; ++r) {
      const int px = P0 + pg * 16 + row4 * 4 + r;
      float v0 = __fadd_rn(__fmul_rn(acc[pg][0][r], inv_[0]), ct_[0]);
      float v1 = __fadd_rn(__fmul_rn(acc[pg][1][r], inv_[1]), ct_[1]);
      v0 = fmaxf(v0, 0.f);
      v1 = fmaxf(v1, 0.f);
      float mx = fmaxf(v0, v1);
#pragma unroll
      for (int sfl = 1; sfl < 16; sfl <<= 1) mx = fmaxf(mx, __shfl_xor(mx, sfl));
      mx = fmaxf(mx, 1e-24f);
      int e = (int)(__float_as_uint(mx) >> 23) - 127;
      float dlt = __uint_as_float((unsigned)(e - 6 + 127) << 23);
      float idlt = __uint_as_float((unsigned)(6 - e + 127) << 23);
      float q0 = fminf(fmaxf(rintf(__fmul_rn(v0, idlt)), -128.f), 127.f);
      float q1 = fminf(fmaxf(rintf(__fmul_rn(v1, idlt)), -128.f), 127.f);
      out16[(size_t)px * 128 + OG + col] = f2bf(__fmul_rn(q0, dlt));
      out16[(size_t)px * 128 + OG + 16 + col] = f2bf(__fmul_rn(q1, dlt));
    }
  }
}

// ---------------------------------------------------------------------------
// conv2: 3x3 im2col GEMM K=1152, 2-phase LDS pipeline.
// Per tap: stage A-tile (64px x 128ch = 16KB) via global_load_lds into dbuf
// LDS (chunk-XOR swizzled); prefetch next tap's B into regs; barrier drains
// both; then 16 ds_read_b128 + 32 MFMAs. XCD-swizzled blockIdx.
// ---------------------------------------------------------------------------
__global__ __launch_bounds__(256, 3) void conv2_im2col(
    const unsigned short* __restrict__ A, const unsigned short* __restrict__ Wq,
    const float* __restrict__ gg, const float* __restrict__ bb,
    const float* __restrict__ mm, const float* __restrict__ vv,
    unsigned short* __restrict__ out16, const unsigned short* __restrict__ zp) {
  __shared__ unsigned short As[2][4][64][32];  // [buf][cb][px][ch], 32KB

  const int t = threadIdx.x;
  const int w = t >> 6, l = t & 63;
  const int col = l & 15, row4 = l >> 4;
  // bijective XCD swizzle: XCD k owns images 8k..8k+7 (a1 slice L2-resident)
  const int bid = blockIdx.x;
  const int P0 = ((bid & 7) * 98 + (bid >> 3)) * 64;
  const int OG = w * 32;
  const int k0 = row4 * 8;

  // staging geometry: thread t stages the 16B chunk at LDS offset t*16 of
  // each cb-plane; swizzle: stored chunk c holds linear chunk c^((px>>1)&3)
  const int spx = t >> 2;
  const int scp = (t & 3) ^ ((spx >> 1) & 3);
  const int sp = P0 + spx;
  const int sn = sp / HW;
  const int shw = sp - sn * HW;
  const int sh = shw / WW, sw = shw - (shw / WW) * WW;
  const size_t nbase = (size_t)sn * HW;

  unsigned short* lds0 = &As[0][0][0][0];
  unsigned short* ldsw = lds0 + (size_t)w * 512;  // wave-uniform staging base

  const unsigned short* bb0 = Wq + (size_t)(OG + col) * 1152 + k0;
  const unsigned short* bb1 = Wq + (size_t)(OG + 16 + col) * 1152 + k0;

  f4v acc[4][2];
#pragma unroll
  for (int pg = 0; pg < 4; ++pg)
#pragma unroll
    for (int og = 0; og < 2; ++og) acc[pg][og] = (f4v){0.f, 0.f, 0.f, 0.f};

  s8v Bcur[8], Bnxt[8];

#define C2_STAGE(tap_, buf_)                                                 \
  {                                                                          \
    const int ty_ = (tap_) / 3, tx_ = (tap_) - ty_ * 3;                      \
    const int h2_ = sh + ty_ - 1, w2_ = sw + tx_ - 1;                        \
    const bool ok_ = ((unsigned)h2_ < 28u) & ((unsigned)w2_ < 28u);          \
    const unsigned short* s0_ =                                              \
        ok_ ? (A + (nbase + h2_ * WW + w2_) * 128 + scp * 8) : (zp + scp * 8);\
    _Pragma("unroll") for (int cb = 0; cb < 4; ++cb)                         \
        gload_lds16(s0_ + cb * 32, ldsw + (buf_)*8192 + cb * 2048);          \
  }

#define C2_LOADB(tap_, B_)                                                   \
  {                                                                          \
    _Pragma("unroll") for (int cb = 0; cb < 4; ++cb) {                       \
      B_[2 * cb] = *(const s8v*)(bb0 + (tap_)*128 + cb * 32);                \
      B_[2 * cb + 1] = *(const s8v*)(bb1 + (tap_)*128 + cb * 32);            \
    }                                                                        \
  }

  C2_STAGE(0, 0);
  C2_LOADB(0, Bcur);
  __syncthreads();  // drains vmcnt: A-tile 0 in LDS, B 0 in regs

#pragma unroll
  for (int tap = 0; tap < 9; ++tap) {
    const int buf = tap & 1;
    if (tap < 8) {
      C2_STAGE(tap + 1, buf ^ 1);  // async, overlaps the 32 MFMAs below
      C2_LOADB(tap + 1, Bnxt);
    }
#pragma unroll
    for (int cb = 0; cb < 4; ++cb) {
#pragma unroll
      for (int pg = 0; pg < 4; ++pg) {
        const int px = pg * 16 + col;
        const s8v af = *(const s8v*)(lds0 + buf * 8192 + cb * 2048 + px * 32 +
                                     (row4 ^ ((px >> 1) & 3)) * 8);
        acc[pg][0] = mfma16(af, Bcur[2 * cb], acc[pg][0]);
        acc[pg][1] = mfma16(af, Bcur[2 * cb + 1], acc[pg][1]);
      }
    }
    __syncthreads();  // next tile ready; all waves done reading buf
    if (tap < 8) {
#pragma unroll
      for (int j = 0; j < 8; ++j) Bcur[j] = Bnxt[j];
    }
  }

  float inv_[2], ct_[2];
#pragma unroll
  for (int og = 0; og < 2; ++og) {
    int o = OG + og * 16 + col;
    float iv = __fdiv_rn(gg[o], sqrtf(__fadd_rn(vv[o], 1e-5f)));
    inv_[og] = iv;
    ct_[og] = __fsub_rn(bb[o], __fmul_rn(mm[o], iv));
  }
#pragma unroll
  for (int pg = 0; pg < 4; ++pg) {
#pragma unroll
    for (int r = 0; r < 4; ++r) {
      const int px = P0 + pg * 16 + row4 * 4 + r;
      float v0 = __fadd_rn(__fmul_rn(acc[pg][0][r], inv_[0]), ct_[0]);
      float v1 = __fadd_rn(__fmul_rn(acc[pg][1][r], inv_[1]), ct_[1]);
      v0 = fmaxf(v0, 0.f);
      v1 = fmaxf(v1, 0.f);
      float mx = fmaxf(v0, v1);
#pragma unroll
      for (int sfl = 1; sfl < 16; sfl <<= 1) mx = fmaxf(mx, __shfl_xor(mx, sfl));
      mx = fmaxf(mx, 1e-24f);
      int e = (int)(__float_as_uint(mx) >> 23) - 127;
      float dlt = __uint_as_float((unsigned)(e - 6 + 127) << 23);
      float idlt = __uint_as_float((unsigned)(6 - e + 127) << 23);
      float q0 = fminf(fmaxf(rintf(__fmul_rn(v0, idlt)), -128.f), 127.f);
      float q1 = fminf(fmaxf(rintf(__fmul_rn(v1, idlt)), -128.f), 127.f);
      out16[(size_t)px * 128 + OG + col] = f2bf(__fmul_rn(q0, dlt));
      out16[(size_t)px * 128 + OG + 16 + col] = f2bf(__fmul_rn(q1, dlt));
    }
  }
}

// ---------------------------------------------------------------------------
// conv3: K=128 GEMM + bn3 + residual + relu + bfp -> out NCHW fp32.
// float4 resid loads / out stores (line-coalesced).
// ---------------------------------------------------------------------------
__global__ __launch_bounds__(256) void conv3_res(
    const unsigned short* __restrict__ A, const unsigned short* __restrict__ Wq,
    const float* __restrict__ gg, const float* __restrict__ bb,
    const float* __restrict__ mm, const float* __restrict__ vv,
    const float* __restrict__ resid, float* __restrict__ outf) {
  const int t = threadIdx.x;
  const int w = t >> 6, l = t & 63;
  const int col = l & 15, row4 = l >> 4;
  const int P0 = blockIdx.x * 64;
  const int OG = blockIdx.y * 128 + w * 32;
  const int k0 = row4 * 8;

  const unsigned short* ab[4];
#pragma unroll
  for (int pg = 0; pg < 4; ++pg)
    ab[pg] = A + (size_t)(P0 + pg * 16 + col) * 128 + k0;
  const unsigned short* b0p = Wq + (size_t)(OG + col) * 128 + k0;
  const unsigned short* b1p = Wq + (size_t)(OG + 16 + col) * 128 + k0;

  f4v acc[4][2];
#pragma unroll
  for (int pg = 0; pg < 4; ++pg)
#pragma unroll
    for (int og = 0; og < 2; ++og) acc[pg][og] = (f4v){0.f, 0.f, 0.f, 0.f};

#pragma unroll
  for (int kb = 0; kb < 4; ++kb) {
    s8v bf0 = *(const s8v*)(b0p + kb * 32);
    s8v bf1 = *(const s8v*)(b1p + kb * 32);
#pragma unroll
    for (int pg = 0; pg < 4; ++pg) {
      s8v af = *(const s8v*)(ab[pg] + kb * 32);
      acc[pg][0] = mfma16(af, bf0, acc[pg][0]);
      acc[pg][1] = mfma16(af, bf1, acc[pg][1]);
    }
  }

  float inv_[2], ct_[2];
#pragma unroll
  for (int og = 0; og < 2; ++og) {
    int o = OG + og * 16 + col;
    float iv = __fdiv_rn(gg[o], sqrtf(__fadd_rn(vv[o], 1e-5f)));
    inv_[og] = iv;
    ct_[og] = __fsub_rn(bb[o], __fmul_rn(mm[o], iv));
  }

#pragma unroll
  for (int pg = 0; pg < 4; ++pg) {
    const int px0 = P0 + pg * 16 + row4 * 4;  // 4 consecutive px, 16B aligned
    const int n = px0 / HW;
    const int hw0 = px0 - n * HW;             // 784 % 16 == 0: no straddle
    const size_t base0 = ((size_t)n * 512 + OG + col) * HW + hw0;
    const size_t base1 = ((size_t)n * 512 + OG + 16 + col) * HW + hw0;
    const float4 r0 = *(const float4*)(resid + base0);
    const float4 r1 = *(const float4*)(resid + base1);
    const float rr0[4] = {r0.x, r0.y, r0.z, r0.w};
    const float rr1[4] = {r1.x, r1.y, r1.z, r1.w};
    float s0[4], s1[4];
#pragma unroll
    for (int r = 0; r < 4; ++r) {
      float v0 = __fadd_rn(__fmul_rn(acc[pg][0][r], inv_[0]), ct_[0]);
      float v1 = __fadd_rn(__fmul_rn(acc[pg][1][r], inv_[1]), ct_[1]);
      v0 = __fadd_rn(v0, rr0[r]);
      v1 = __fadd_rn(v1, rr1[r]);
      v0 = fmaxf(v0, 0.f);
      v1 = fmaxf(v1, 0.f);
      float mx = fmaxf(v0, v1);
#pragma unroll
      for (int sfl = 1; sfl < 16; sfl <<= 1) mx = fmaxf(mx, __shfl_xor(mx, sfl));
      mx = fmaxf(mx, 1e-24f);
      int e = (int)(__float_as_uint(mx) >> 23) - 127;
      float dlt = __uint_as_float((unsigned)(e - 6 + 127) << 23);
      float idlt = __uint_as_float((unsigned)(6 - e + 127) << 23);
      float q0 = fminf(fmaxf(rintf(__fmul_rn(v0, idlt)), -128.f), 127.f);
      float q1 = fminf(fmaxf(rintf(__fmul_rn(v1, idlt)), -128.f), 127.f);
      s0[r] = __fmul_rn(q0, dlt);
      s1[r] = __fmul_rn(q1, dlt);
    }
    *(float4*)(outf + base0) = make_float4(s0[0], s0[1], s0[2], s0[3]);
    *(float4*)(outf + base1) = make_float4(s1[0], s1[1], s1[2], s1[3]);
  }
}

// ---------------------------------------------------------------------------
extern "C" void kernel_launch(void* const* d_in, const int* in_sizes, int n_in,
                              void* d_out, int out_size, void* d_ws, size_t ws_size,
                              hipStream_t stream) {
  (void)in_sizes; (void)n_in; (void)out_size; (void)ws_size;
  const float* x = (const float*)d_in[0];
  const float* w1 = (const float*)d_in[1];
  const float* w2 = (const float*)d_in[2];
  const float* w3 = (const float*)d_in[3];
  const float* bn1g = (const float*)d_in[4];
  const float* bn1b = (const float*)d_in[5];
  const float* bn1m = (const float*)d_in[6];
  const float* bn1v = (const float*)d_in[7];
  const float* bn2g = (const float*)d_in[8];
  const float* bn2b = (const float*)d_in[9];
  const float* bn2m = (const float*)d_in[10];
  const float* bn2v = (const float*)d_in[11];
  const float* bn3g = (const float*)d_in[12];
  const float* bn3b = (const float*)d_in[13];
  const float* bn3m = (const float*)d_in[14];
  const float* bn3v = (const float*)d_in[15];

  unsigned short* ws = (unsigned short*)d_ws;
  unsigned short* zp = ws;                          // 256 shorts (zero page)
  unsigned short* w1d = ws + 256;                   // [128][1024]
  unsigned short* w2q = w1d + 128 * 1024;           // [128][1152]
  unsigned short* w3q = w2q + 128 * 1152;           // [512][128]
  unsigned short* a1 = w3q + 512 * 128;             // [50176][128]
  unsigned short* a2 = a1 + (size_t)PTOT * 128;     // [50176][128]
  // total ~26.4 MB

  hipMemsetAsync(zp, 0, 512, stream);

  wq1_kernel<<<8, 256, 0, stream>>>(w1, w1d);
  wq2_kernel<<<18, 256, 0, stream>>>(w2, w2q);
  wq3_kernel<<<8, 256, 0, stream>>>(w3, w3q);

  conv1_fused<<<dim3(PTOT / 64, 1), 256, 0, stream>>>(
      x, w1d, bn1g, bn1b, bn1m, bn1v, a1);
  conv2_im2col<<<dim3(PTOT / 64, 1), 256, 0, stream>>>(
      a1, w2q, bn2g, bn2b, bn2m, bn2v, a2, zp);
  conv3_res<<<dim3(PTOT / 64, 4), 256, 0, stream>>>(
      a2, w3q, bn3g, bn3b, bn3m, bn3v, x, (float*)d_out);
}